// Round 4
// baseline (296.880 us; speedup 1.0000x reference)
//
#include <hip/hip_runtime.h>
#include <hip/hip_bf16.h>
#include <string.h>

typedef __attribute__((ext_vector_type(8))) short short8;
typedef __attribute__((ext_vector_type(4))) float floatx4;

// B=32, T=2048, D=512, U=512, M = B*T = 65536

__device__ inline uint packbf2(float lo, float hi) {
    __hip_bfloat162 h = __float22bfloat162_rn(make_float2(lo, hi));
    uint r; memcpy(&r, &h, 4); return r;
}

__device__ inline float tanh_fast(float x) {
    x = fminf(15.f, fmaxf(-15.f, x));
    float e = __expf(2.f * x);
    return __fdividef(e - 1.f, e + 1.f);
}

// async global->LDS 16B: dest = wave-uniform lds base + lane*16 (linear).
__device__ inline void gload_lds16(const float* g, float* l) {
    __builtin_amdgcn_global_load_lds(
        (const __attribute__((address_space(1))) unsigned int*)g,
        (__attribute__((address_space(3))) unsigned int*)l,
        16, 0, 0);
}

// ---- kernel 0: fused prep.
// blocks 0..127:   pack W1_enc -> bf16 B-frag chunks (Wp)
// blocks 128..383: dec[b][u] = h_dec[b]·W1_dec[:,u] + b1[u]
// blocks 384..447: zero ctx (for kctx2's atomicAdd finish)
__global__ void kprep(const float* __restrict__ W1, const float* __restrict__ hdec,
                      const float* __restrict__ b1, ushort* __restrict__ Wp,
                      float* __restrict__ dec, float* __restrict__ ctx) {
    __shared__ float red[4][64];
    int tid = threadIdx.x;
    if (blockIdx.x < 128) {
        int wid = blockIdx.x * 4 + (tid >> 6);       // 0..511 chunks
        int l = tid & 63;
        int kc = wid >> 5, ng = wid & 31;
        int m = l & 15, g = l >> 4;
        const float* src = W1 + (size_t)(kc * 32 + g * 8) * 512 + ng * 16 + m;
        uint u4[4];
        #pragma unroll
        for (int e = 0; e < 4; ++e)
            u4[e] = packbf2(src[(size_t)(2 * e) * 512], src[(size_t)(2 * e + 1) * 512]);
        *(uint4*)(Wp + (size_t)wid * 512 + l * 8) = *(uint4*)u4;
    } else if (blockIdx.x < 384) {
        int bid = blockIdx.x - 128;                  // 0..255
        int b = bid >> 3, ug = bid & 7;
        int u = ug * 64 + (tid & 63), dq = tid >> 6;
        const float* hb = hdec + b * 512 + dq * 128;
        const float* w = W1 + (size_t)(512 + dq * 128) * 512 + u;
        float a = 0.f;
        #pragma unroll 8
        for (int d = 0; d < 128; ++d)
            a += hb[d] * w[(size_t)d * 512];
        red[dq][tid & 63] = a;
        __syncthreads();
        if (tid < 64)
            dec[b * 512 + ug * 64 + tid] =
                red[0][tid] + red[1][tid] + red[2][tid] + red[3][tid] + b1[ug * 64 + tid];
    } else {
        ctx[(blockIdx.x - 384) * 256 + tid] = 0.f;   // 64 blocks x 256 = 16384
    }
}

// ---- kernel 1: fused GEMM + tanh + dot(W2) -> e2 (pre-relu logits)
// 512 thr = 8 waves; block tile 64 rows x 512 cols (full U) x K=512.
// 2-phase global_load_lds template (m97 structure):
//   STAGE(next chunk, issue-only) -> compute(cur) -> __syncthreads (vmcnt drain)
// A staged as fp32 (32 KB/chunk, x2 dbuf), cvt->bf16 at fragment read.
// XOR swizzle (both-sides): LDS dest linear, global source pre-swizzled with
// loff = d ^ (((d>>9)&7)<<4); fragment ds_read applies the same XOR.
// Zero VGPR staging => fits 128-reg cap at launch_bounds(512,4), no spill.
__global__ __launch_bounds__(512, 4) void kgemm(
        const float* __restrict__ A, const ushort* __restrict__ Wp,
        const float* __restrict__ dec, const float* __restrict__ W2,
        float* __restrict__ e2) {
    __shared__ __align__(16) float Asf[2][8192];     // 2 x 32 KB fp32 (64 rows x 128 k)
    __shared__ float red[8][64];
    const int tid = threadIdx.x;
    const int lane = tid & 63, wave = tid >> 6;
    const int rowbase = blockIdx.x * 64;
    const int bIdx = blockIdx.x >> 5;                // 32 blocks per batch
    const int m = lane & 15, g = lane >> 4;

    // issue 4 global_load_lds (16B each) for chunk cc into buffer cb.
    // LDS byte d = wave*4096 + is*1024 + lane*16 (linear per wave-issue).
    // row(d) = wave*8 + is*2 + (lane>>5); src col pre-swizzled by row XOR.
    auto stage = [&](int cb, int cc) {
        #pragma unroll
        for (int is = 0; is < 4; ++is) {
            int row = wave * 8 + is * 2 + (lane >> 5);
            int colb = ((lane & 31) * 16) ^ ((row & 7) << 4);
            const float* gp = A + (size_t)(rowbase + row) * 512 + cc * 128 + (colb >> 2);
            float* lp = &Asf[cb][(wave * 4096 + is * 1024) >> 2];
            gload_lds16(gp, lp);
        }
    };

    floatx4 acc[4][4];
    #pragma unroll
    for (int i = 0; i < 4; i++)
        #pragma unroll
        for (int j = 0; j < 4; j++) acc[i][j] = (floatx4){0.f, 0.f, 0.f, 0.f};

    const int ng0 = wave * 4;
    const ushort* wpb = Wp + (size_t)ng0 * 512 + lane * 8;

    auto compute = [&](int cc, int cb) {
        #pragma unroll
        for (int s = 0; s < 4; ++s) {
            short8 afr[4];
            #pragma unroll
            for (int i = 0; i < 4; ++i) {
                int r = i * 16 + m;
                int xr = (r & 7) << 4;
                int base = r * 512 + s * 128 + g * 32;
                int o0 = base ^ xr;
                int o1 = (base + 16) ^ xr;
                float4 f0 = *(const float4*)((const char*)Asf[cb] + o0);
                float4 f1 = *(const float4*)((const char*)Asf[cb] + o1);
                uint4 u;
                u.x = packbf2(f0.x, f0.y); u.y = packbf2(f0.z, f0.w);
                u.z = packbf2(f1.x, f1.y); u.w = packbf2(f1.z, f1.w);
                memcpy(&afr[i], &u, 16);
            }
            const int kc = cc * 4 + s;
            #pragma unroll
            for (int j = 0; j < 4; ++j) {
                short8 bfr = *(const short8*)&wpb[(size_t)(kc * 32 + j) * 512];
                #pragma unroll
                for (int i = 0; i < 4; ++i)
                    acc[i][j] = __builtin_amdgcn_mfma_f32_16x16x32_bf16(afr[i], bfr, acc[i][j], 0, 0, 0);
            }
        }
    };

    // prologue: chunk 0 staged, wait, then pipeline: stage(next) -> compute(cur)
    stage(0, 0);
    __syncthreads();                 // drains vmcnt(0): chunk 0 in LDS
    stage(1, 1);
    compute(0, 0);
    __syncthreads();                 // chunk 1 landed (covered by compute 0)
    stage(0, 2);
    compute(1, 1);
    __syncthreads();
    stage(1, 3);
    compute(2, 0);
    __syncthreads();
    compute(3, 1);

    // epilogue: z += dec; p = sum_u tanh(z)*W2[u]; reduce 16 lanes + 8 waves
    float w2v[4], dv[4];
    #pragma unroll
    for (int j = 0; j < 4; j++) {
        int n = wave * 64 + j * 16 + m;
        w2v[j] = W2[n];
        dv[j]  = dec[bIdx * 512 + n];
    }
    #pragma unroll
    for (int i = 0; i < 4; i++) {
        #pragma unroll
        for (int r = 0; r < 4; r++) {
            float p = 0.f;
            #pragma unroll
            for (int j = 0; j < 4; j++)
                p += tanh_fast(acc[i][j][r] + dv[j]) * w2v[j];
            p += __shfl_xor(p, 1, 16);
            p += __shfl_xor(p, 2, 16);
            p += __shfl_xor(p, 4, 16);
            p += __shfl_xor(p, 8, 16);
            if (m == 0) red[wave][i * 16 + g * 4 + r] = p;
        }
    }
    __syncthreads();
    if (tid < 64) {
        float s = 0.f;
        #pragma unroll
        for (int w = 0; w < 8; ++w) s += red[w][tid];
        e2[rowbase + tid] = s;
    }
}

// ---- kernel 2: fused softmax + partial context -> atomicAdd into ctx.
// Block (b,ch): recompute row softmax stats from e2 (fixed reduction order =>
// bitwise-identical across blocks of same b), write own 64-wide attn slice,
// then ctx[b][:] += sum_{t in chunk} attn*h_enc (atomic, fp32).
__global__ __launch_bounds__(512) void kctx2(const float* __restrict__ A,
        const float* __restrict__ e2, const float* __restrict__ b2,
        float* __restrict__ attn, float* __restrict__ ctx) {
    __shared__ float at[64];
    __shared__ float4 red[3][128];
    __shared__ float smax[8], ssum[8];
    int b = blockIdx.x, ch = blockIdx.y, tid = threadIdx.x;
    int lane = tid & 63, wave = tid >> 6;
    float b2v = b2[0];
    const float* erow = e2 + b * 2048;

    float f[4];
    float mx = 0.f;                                   // relu values >= 0
    #pragma unroll
    for (int i = 0; i < 4; i++) {
        f[i] = fmaxf(erow[i * 512 + tid] + b2v, 0.f);
        mx = fmaxf(mx, f[i]);
    }
    #pragma unroll
    for (int off = 1; off < 64; off <<= 1) mx = fmaxf(mx, __shfl_xor(mx, off));
    if (lane == 0) smax[wave] = mx;
    __syncthreads();
    #pragma unroll
    for (int w = 0; w < 8; ++w) mx = fmaxf(mx, smax[w]);
    float s = 0.f;
    #pragma unroll
    for (int i = 0; i < 4; i++) s += __expf(f[i] - mx);
    #pragma unroll
    for (int off = 1; off < 64; off <<= 1) s += __shfl_xor(s, off);
    if (lane == 0) ssum[wave] = s;
    __syncthreads();
    s = 0.f;
    #pragma unroll
    for (int w = 0; w < 8; ++w) s += ssum[w];
    float inv = 1.f / s;

    if (tid < 64) {
        float z = fmaxf(erow[ch * 64 + tid] + b2v, 0.f);
        float a = __expf(z - mx) * inv;
        at[tid] = a;
        attn[b * 2048 + ch * 64 + tid] = a;
    }
    __syncthreads();

    int dt = tid & 127, th = tid >> 7;               // th in 0..3, 16 t each
    const float* base = A + ((size_t)b * 2048 + ch * 64 + th * 16) * 512 + dt * 4;
    const float* aw = at + th * 16;
    float4 acc = (float4){0.f, 0.f, 0.f, 0.f};
    #pragma unroll
    for (int tt = 0; tt < 16; ++tt) {
        float a = aw[tt];
        float4 h = *(const float4*)(base + (size_t)tt * 512);
        acc.x += a * h.x; acc.y += a * h.y; acc.z += a * h.z; acc.w += a * h.w;
    }
    if (th) red[th - 1][dt] = acc;
    __syncthreads();
    if (th == 0) {
        float4 o0 = red[0][dt], o1 = red[1][dt], o2 = red[2][dt];
        float* cp = ctx + (size_t)b * 512 + dt * 4;
        atomicAdd(cp + 0, acc.x + o0.x + o1.x + o2.x);
        atomicAdd(cp + 1, acc.y + o0.y + o1.y + o2.y);
        atomicAdd(cp + 2, acc.z + o0.z + o1.z + o2.z);
        atomicAdd(cp + 3, acc.w + o0.w + o1.w + o2.w);
    }
}

extern "C" void kernel_launch(void* const* d_in, const int* in_sizes, int n_in,
                              void* d_out, int out_size, void* d_ws, size_t ws_size,
                              hipStream_t stream) {
    const float* h_enc = (const float*)d_in[0];
    const float* h_dec = (const float*)d_in[1];
    const float* W1    = (const float*)d_in[2];
    const float* b1    = (const float*)d_in[3];
    const float* W2    = (const float*)d_in[4];
    const float* b2    = (const float*)d_in[5];
    float* out  = (float*)d_out;
    float* ctx  = out;              // 32*512
    float* attn = out + 32 * 512;   // 32*2048

    char* ws = (char*)d_ws;
    ushort* Wp = (ushort*)ws;                                    // 512 KB
    float* dec  = (float*)(ws + (512 * 512 * 2));                // 64 KB
    float* e2   = (float*)(ws + (512 * 512 * 2) + (32 * 512 * 4));  // 256 KB

    kprep<<<448, 256, 0, stream>>>(W1, h_dec, b1, Wp, dec, ctx);
    kgemm<<<1024, 512, 0, stream>>>(h_enc, Wp, dec, W2, e2);
    dim3 g3(32, 32);
    kctx2<<<g3, 512, 0, stream>>>(h_enc, e2, b2, attn, ctx);
}

// Round 5
// 273.455 us; speedup vs baseline: 1.0857x; 1.0857x over previous
//
#include <hip/hip_runtime.h>
#include <hip/hip_bf16.h>
#include <string.h>

typedef __attribute__((ext_vector_type(8))) short short8;
typedef __attribute__((ext_vector_type(4))) float floatx4;

// B=32, T=2048, D=512, U=512, M = B*T = 65536

__device__ inline uint packbf2(float lo, float hi) {
    __hip_bfloat162 h = __float22bfloat162_rn(make_float2(lo, hi));
    uint r; memcpy(&r, &h, 4); return r;
}

__device__ inline float tanh_fast(float x) {
    x = fminf(15.f, fmaxf(-15.f, x));
    float e = __expf(2.f * x);
    return __fdividef(e - 1.f, e + 1.f);
}

// ---- kernel 0: fused prep.
// blocks 0..127:   pack W1_enc -> bf16 B-frag chunks (Wp)
// blocks 128..383: dec[b][u] = h_dec[b]·W1_dec[:,u] + b1[u]
// blocks 384..447: zero ctx (for kctx2's atomicAdd finish)
// blocks 448..511: zero e2  (for kgemm's atomicAdd epilogue)
__global__ void kprep(const float* __restrict__ W1, const float* __restrict__ hdec,
                      const float* __restrict__ b1, ushort* __restrict__ Wp,
                      float* __restrict__ dec, float* __restrict__ ctx,
                      float* __restrict__ e2) {
    __shared__ float red[4][64];
    int tid = threadIdx.x;
    if (blockIdx.x < 128) {
        int wid = blockIdx.x * 4 + (tid >> 6);       // 0..511 chunks
        int l = tid & 63;
        int kc = wid >> 5, ng = wid & 31;
        int m = l & 15, g = l >> 4;
        const float* src = W1 + (size_t)(kc * 32 + g * 8) * 512 + ng * 16 + m;
        uint u4[4];
        #pragma unroll
        for (int e = 0; e < 4; ++e)
            u4[e] = packbf2(src[(size_t)(2 * e) * 512], src[(size_t)(2 * e + 1) * 512]);
        *(uint4*)(Wp + (size_t)wid * 512 + l * 8) = *(uint4*)u4;
    } else if (blockIdx.x < 384) {
        int bid = blockIdx.x - 128;                  // 0..255
        int b = bid >> 3, ug = bid & 7;
        int u = ug * 64 + (tid & 63), dq = tid >> 6;
        const float* hb = hdec + b * 512 + dq * 128;
        const float* w = W1 + (size_t)(512 + dq * 128) * 512 + u;
        float a = 0.f;
        #pragma unroll 8
        for (int d = 0; d < 128; ++d)
            a += hb[d] * w[(size_t)d * 512];
        red[dq][tid & 63] = a;
        __syncthreads();
        if (tid < 64)
            dec[b * 512 + ug * 64 + tid] =
                red[0][tid] + red[1][tid] + red[2][tid] + red[3][tid] + b1[ug * 64 + tid];
    } else if (blockIdx.x < 448) {
        ctx[(blockIdx.x - 384) * 256 + tid] = 0.f;   // 64 blocks x 256 = 16384
    } else {
        int idx = (blockIdx.x - 448) * 256 + tid;    // 64 blocks x 256 float4 = 65536 f
        ((float4*)e2)[idx] = (float4){0.f, 0.f, 0.f, 0.f};
    }
}

// ---- kernel 1: fused GEMM + tanh + dot(W2) -> e2 partials (atomicAdd)
// grid 2048: bx>>1 = 64-row slab, bx&1 = 256-col half. 512 thr = 8 waves.
// Wave tile 64x32 (acc[4][2] = 32 regs) frees registers for a software-
// pipelined B prefetch (bnxt loaded one kc ahead) hiding L2 latency.
// A staged once to LDS in frag order (round-0 proven, conflict-free).
__global__ __launch_bounds__(512, 4) void kgemm(
        const float* __restrict__ A, const ushort* __restrict__ Wp,
        const float* __restrict__ dec, const float* __restrict__ W2,
        float* __restrict__ e2) {
    __shared__ __align__(16) ushort As[32768];   // 64 KB: 64 rows x 512 k bf16
    __shared__ float red[8][64];
    const int tid = threadIdx.x;
    const int bx = blockIdx.x;
    const int rowbase = (bx >> 1) * 64;
    const int nhalf = bx & 1;
    const int bIdx = bx >> 6;                    // batch = rowbase/2048

    // stage A tile: 64 rows x 512 k, fp32 -> bf16, fragment-chunk order
    #pragma unroll
    for (int p = 0; p < 8; ++p) {
        int s = tid + 512 * p;                   // 0..4095 lane-slots
        int chunk = s >> 6, l = s & 63;
        int i = chunk >> 4, kcc = chunk & 15;
        int mm = l & 15, gg = l >> 4;
        const float* gp = A + (size_t)(rowbase + i * 16 + mm) * 512 + kcc * 32 + gg * 8;
        float4 f0 = *(const float4*)gp;
        float4 f1 = *(const float4*)(gp + 4);
        uint4 u;
        u.x = packbf2(f0.x, f0.y); u.y = packbf2(f0.z, f0.w);
        u.z = packbf2(f1.x, f1.y); u.w = packbf2(f1.z, f1.w);
        *(uint4*)&As[chunk * 512 + l * 8] = u;
    }
    __syncthreads();

    const int lane = tid & 63, wave = tid >> 6;
    const int m = lane & 15, g = lane >> 4;
    const int ng0 = nhalf * 16 + wave * 2;       // wave covers 2 16-col groups

    floatx4 acc[4][2];
    #pragma unroll
    for (int i = 0; i < 4; i++)
        #pragma unroll
        for (int j = 0; j < 2; j++) acc[i][j] = (floatx4){0.f, 0.f, 0.f, 0.f};

    #define LDB(kc, j) (*(const short8*)&Wp[(size_t)((kc) * 32 + ng0 + (j)) * 512 + lane * 8])

    short8 bc0 = LDB(0, 0), bc1 = LDB(0, 1);
    #pragma unroll
    for (int kc = 0; kc < 16; ++kc) {
        short8 bn0, bn1;
        if (kc < 15) { bn0 = LDB(kc + 1, 0); bn1 = LDB(kc + 1, 1); }
        short8 afr[4];
        #pragma unroll
        for (int i = 0; i < 4; ++i)
            afr[i] = *(const short8*)&As[(i * 16 + kc) * 512 + lane * 8];
        #pragma unroll
        for (int i = 0; i < 4; ++i) {
            acc[i][0] = __builtin_amdgcn_mfma_f32_16x16x32_bf16(afr[i], bc0, acc[i][0], 0, 0, 0);
            acc[i][1] = __builtin_amdgcn_mfma_f32_16x16x32_bf16(afr[i], bc1, acc[i][1], 0, 0, 0);
        }
        bc0 = bn0; bc1 = bn1;
    }
    #undef LDB

    // epilogue: z += dec; partial p = sum_{u in wave cols} tanh(z)*W2[u]
    float w2v[2], dv[2];
    #pragma unroll
    for (int j = 0; j < 2; j++) {
        int n = nhalf * 256 + wave * 32 + j * 16 + m;
        w2v[j] = W2[n];
        dv[j]  = dec[bIdx * 512 + n];
    }
    #pragma unroll
    for (int i = 0; i < 4; i++) {
        #pragma unroll
        for (int r = 0; r < 4; r++) {
            float p = 0.f;
            #pragma unroll
            for (int j = 0; j < 2; j++)
                p += tanh_fast(acc[i][j][r] + dv[j]) * w2v[j];
            p += __shfl_xor(p, 1, 16);
            p += __shfl_xor(p, 2, 16);
            p += __shfl_xor(p, 4, 16);
            p += __shfl_xor(p, 8, 16);
            if (m == 0) red[wave][i * 16 + g * 4 + r] = p;
        }
    }
    __syncthreads();
    if (tid < 64) {
        float s = 0.f;
        #pragma unroll
        for (int w = 0; w < 8; ++w) s += red[w][tid];
        atomicAdd(&e2[rowbase + tid], s);        // combine 2 col-half blocks
    }
}

// ---- kernel 2: fused softmax + partial context -> atomicAdd into ctx.
// Block (b,ch): recompute row softmax stats from e2 (fixed reduction order =>
// identical across blocks of same b), write own 64-wide attn slice,
// then ctx[b][:] += sum_{t in chunk} attn*h_enc (atomic, fp32).
__global__ __launch_bounds__(512) void kctx2(const float* __restrict__ A,
        const float* __restrict__ e2, const float* __restrict__ b2,
        float* __restrict__ attn, float* __restrict__ ctx) {
    __shared__ float at[64];
    __shared__ float4 red[3][128];
    __shared__ float smax[8], ssum[8];
    int b = blockIdx.x, ch = blockIdx.y, tid = threadIdx.x;
    int lane = tid & 63, wave = tid >> 6;
    float b2v = b2[0];
    const float* erow = e2 + b * 2048;

    float f[4];
    float mx = 0.f;                                   // relu values >= 0
    #pragma unroll
    for (int i = 0; i < 4; i++) {
        f[i] = fmaxf(erow[i * 512 + tid] + b2v, 0.f);
        mx = fmaxf(mx, f[i]);
    }
    #pragma unroll
    for (int off = 1; off < 64; off <<= 1) mx = fmaxf(mx, __shfl_xor(mx, off));
    if (lane == 0) smax[wave] = mx;
    __syncthreads();
    #pragma unroll
    for (int w = 0; w < 8; ++w) mx = fmaxf(mx, smax[w]);
    float s = 0.f;
    #pragma unroll
    for (int i = 0; i < 4; i++) s += __expf(f[i] - mx);
    #pragma unroll
    for (int off = 1; off < 64; off <<= 1) s += __shfl_xor(s, off);
    if (lane == 0) ssum[wave] = s;
    __syncthreads();
    s = 0.f;
    #pragma unroll
    for (int w = 0; w < 8; ++w) s += ssum[w];
    float inv = 1.f / s;

    if (tid < 64) {
        float z = fmaxf(erow[ch * 64 + tid] + b2v, 0.f);
        float a = __expf(z - mx) * inv;
        at[tid] = a;
        attn[b * 2048 + ch * 64 + tid] = a;
    }
    __syncthreads();

    int dt = tid & 127, th = tid >> 7;               // th in 0..3, 16 t each
    const float* base = A + ((size_t)b * 2048 + ch * 64 + th * 16) * 512 + dt * 4;
    const float* aw = at + th * 16;
    float4 acc = (float4){0.f, 0.f, 0.f, 0.f};
    #pragma unroll
    for (int tt = 0; tt < 16; ++tt) {
        float a = aw[tt];
        float4 h = *(const float4*)(base + (size_t)tt * 512);
        acc.x += a * h.x; acc.y += a * h.y; acc.z += a * h.z; acc.w += a * h.w;
    }
    if (th) red[th - 1][dt] = acc;
    __syncthreads();
    if (th == 0) {
        float4 o0 = red[0][dt], o1 = red[1][dt], o2 = red[2][dt];
        float* cp = ctx + (size_t)b * 512 + dt * 4;
        atomicAdd(cp + 0, acc.x + o0.x + o1.x + o2.x);
        atomicAdd(cp + 1, acc.y + o0.y + o1.y + o2.y);
        atomicAdd(cp + 2, acc.z + o0.z + o1.z + o2.z);
        atomicAdd(cp + 3, acc.w + o0.w + o1.w + o2.w);
    }
}

extern "C" void kernel_launch(void* const* d_in, const int* in_sizes, int n_in,
                              void* d_out, int out_size, void* d_ws, size_t ws_size,
                              hipStream_t stream) {
    const float* h_enc = (const float*)d_in[0];
    const float* h_dec = (const float*)d_in[1];
    const float* W1    = (const float*)d_in[2];
    const float* b1    = (const float*)d_in[3];
    const float* W2    = (const float*)d_in[4];
    const float* b2    = (const float*)d_in[5];
    float* out  = (float*)d_out;
    float* ctx  = out;              // 32*512
    float* attn = out + 32 * 512;   // 32*2048

    char* ws = (char*)d_ws;
    ushort* Wp = (ushort*)ws;                                    // 512 KB
    float* dec  = (float*)(ws + (512 * 512 * 2));                // 64 KB
    float* e2   = (float*)(ws + (512 * 512 * 2) + (32 * 512 * 4));  // 256 KB

    kprep<<<512, 256, 0, stream>>>(W1, h_dec, b1, Wp, dec, ctx, e2);
    kgemm<<<2048, 512, 0, stream>>>(h_enc, Wp, dec, W2, e2);
    dim3 g3(32, 32);
    kctx2<<<g3, 512, 0, stream>>>(h_enc, e2, b2, attn, ctx);
}